// Round 8
// baseline (142.203 us; speedup 1.0000x reference)
//
#include <hip/hip_runtime.h>
#include <hip/hip_bf16.h>
#include <hip/hip_fp16.h>

typedef _Float16 f16x8 __attribute__((ext_vector_type(8)));
typedef _Float16 f16x4 __attribute__((ext_vector_type(4)));
typedef _Float16 f16x2 __attribute__((ext_vector_type(2)));
typedef float f32x4 __attribute__((ext_vector_type(4)));
typedef float f32x16 __attribute__((ext_vector_type(16)));
typedef unsigned int u32x4 __attribute__((ext_vector_type(4)));

#define MFMA16(a, b, c) __builtin_amdgcn_mfma_f32_16x16x32_f16(a, b, c, 0, 0, 0)
#define MFMA32(a, b, c) __builtin_amdgcn_mfma_f32_32x32x16_f16(a, b, c, 0, 0, 0)

// log2(e) / sqrt(1024)
#define C1 0.045084220027780106f

// ---------------------------------------------------------------------------
// convert f32 -> fp16 for Q, K, Wq, Wk, Wv into one contiguous ws region
// ---------------------------------------------------------------------------
__global__ void cvt_all(const float* __restrict__ Q, const float* __restrict__ K,
                        const float* __restrict__ Wq, const float* __restrict__ Wk,
                        const float* __restrict__ Wv, _Float16* __restrict__ dst) {
    int i = blockIdx.x * blockDim.x + threadIdx.x;  // i indexes groups of 8 f32
    const float* s;
    int off;
    if (i < 524288)       { s = Q;  off = 0;       }
    else if (i < 1048576) { s = K;  off = 524288;  }
    else if (i < 1179648) { s = Wq; off = 1048576; }
    else if (i < 1310720) { s = Wk; off = 1179648; }
    else                  { s = Wv; off = 1310720; }
    int j = i - off;
    float4 a = ((const float4*)s)[2 * j];
    float4 b = ((const float4*)s)[2 * j + 1];
    f16x8 h;
    h[0] = (_Float16)a.x; h[1] = (_Float16)a.y; h[2] = (_Float16)a.z; h[3] = (_Float16)a.w;
    h[4] = (_Float16)b.x; h[5] = (_Float16)b.y; h[6] = (_Float16)b.z; h[7] = (_Float16)b.w;
    ((f16x8*)dst)[i] = h;
}

// ---------------------------------------------------------------------------
// projection GEMM: C[m,n] = A[m,:]·W[n,:] + bias[n]
// Outputs are written in ATTENTION-FRAGMENT-TILED layouts so that every attn
// fragment load is one fully-coalesced 1KB global_load_dwordx4:
//  qT[b*16+h][qt 32][dc 4][q5 32][hi 2][j 8]        (A-frag rows=q, k-dim=d)
//  kT[b*16+h][w 8][kt 4][dc 4][q5 32][hi 2][j 8]    (A-frag rows=k, k-dim=d)
//  vT[b*16+h][w 8][kt 4][dh 2][ks 2][q5 32][hi 2][j 8] (B-frag cols=d, k=attn-k)
// ---------------------------------------------------------------------------
__device__ __forceinline__ void gl_lds16(const void* g, void* l) {
    __builtin_amdgcn_global_load_lds(
        (const __attribute__((address_space(1))) void*)g,
        (__attribute__((address_space(3))) void*)l, 16, 0, 0);
}

__global__ __launch_bounds__(256) void proj_gemm(
    const _Float16* __restrict__ Qh, const _Float16* __restrict__ Kh,
    const _Float16* __restrict__ Wqh, const _Float16* __restrict__ Wkh,
    const _Float16* __restrict__ Wvh,
    const float* __restrict__ bq, const float* __restrict__ bk,
    const float* __restrict__ bv,
    _Float16* __restrict__ qT, _Float16* __restrict__ kT,
    _Float16* __restrict__ vT) {
    const int z = blockIdx.z;
    const _Float16* A = (z == 0) ? Qh : Kh;
    const _Float16* W = (z == 0) ? Wqh : (z == 1 ? Wkh : Wvh);
    const float* bias = (z == 0) ? bq : (z == 1 ? bk : bv);

    __shared__ __align__(16) _Float16 At[128 * 32];
    __shared__ __align__(16) _Float16 Bt[128 * 32];

    const int tid = threadIdx.x;
    const int w = tid >> 6, lane = tid & 63;
    const int g = lane >> 4, c = lane & 15;
    const int m0 = blockIdx.x * 128, n0 = blockIdx.y * 128;
    const int wm = (w & 1) * 64, wn = (w >> 1) * 64;
    const int srow = w * 32 + (lane >> 2);
    const int scol = (lane & 3) * 8;  // in halves

    f32x4 acc[4][4] = {};

    for (int k0 = 0; k0 < 1024; k0 += 32) {
        __syncthreads();
#pragma unroll
        for (int t = 0; t < 2; ++t) {
            int r = srow + t * 16;
            gl_lds16(A + (size_t)(m0 + r) * 1024 + k0 + scol, &At[(w * 2 + t) * 512]);
            gl_lds16(W + (size_t)(n0 + r) * 1024 + k0 + scol, &Bt[(w * 2 + t) * 512]);
        }
        __syncthreads();
        f16x8 af[4], bf[4];
#pragma unroll
        for (int mt = 0; mt < 4; ++mt) af[mt] = *(const f16x8*)&At[(wm + mt * 16 + c) * 32 + g * 8];
#pragma unroll
        for (int nt = 0; nt < 4; ++nt) bf[nt] = *(const f16x8*)&Bt[(wn + nt * 16 + c) * 32 + g * 8];
#pragma unroll
        for (int mt = 0; mt < 4; ++mt)
#pragma unroll
            for (int nt = 0; nt < 4; ++nt)
                acc[mt][nt] = MFMA16(af[mt], bf[nt], acc[mt][nt]);
    }

    if (z == 0) {
        // q: [head][qt][dc][q5][hi][j], scalar stores
#pragma unroll
        for (int mt = 0; mt < 4; ++mt)
#pragma unroll
            for (int nt = 0; nt < 4; ++nt) {
                int col = n0 + wn + nt * 16 + c;
                int hh = col >> 6, dd = col & 63;
                int dc = dd >> 4, hi2 = (dd >> 3) & 1, j = dd & 7;
                float bb = bias[col];
                int row0 = m0 + wm + mt * 16 + g * 4;
                int bbi = row0 >> 10;
                int qtq = (row0 >> 5) & 31;
                int q50 = row0 & 31;
                size_t base = ((((size_t)(bbi * 16 + hh) * 32 + qtq) * 4 + dc) * 32) * 16 +
                              hi2 * 8 + j;
#pragma unroll
                for (int i = 0; i < 4; ++i)
                    qT[base + (size_t)(q50 + i) * 16] = (_Float16)(acc[mt][nt][i] + bb);
            }
    } else if (z == 1) {
        // k: [head][w][kt][dc][q5][hi][j], scalar stores
#pragma unroll
        for (int mt = 0; mt < 4; ++mt)
#pragma unroll
            for (int nt = 0; nt < 4; ++nt) {
                int col = n0 + wn + nt * 16 + c;
                int hh = col >> 6, dd = col & 63;
                int dc = dd >> 4, hi2 = (dd >> 3) & 1, j = dd & 7;
                float bb = bias[col];
                int row0 = m0 + wm + mt * 16 + g * 4;
                int bbi = row0 >> 10, nn = row0 & 1023;
                int wa = nn >> 7, kt = (nn >> 5) & 3, q50 = nn & 31;
                size_t base = (((((size_t)(bbi * 16 + hh) * 8 + wa) * 4 + kt) * 4 + dc) * 32) * 16 +
                              hi2 * 8 + j;
#pragma unroll
                for (int i = 0; i < 4; ++i)
                    kT[base + (size_t)(q50 + i) * 16] = (_Float16)(acc[mt][nt][i] + bb);
            }
    } else {
        // v: [head][w][kt][dh][ks][q5][hi][j], f16x4 stores (j contiguous)
#pragma unroll
        for (int mt = 0; mt < 4; ++mt)
#pragma unroll
            for (int nt = 0; nt < 4; ++nt) {
                int col = n0 + wn + nt * 16 + c;
                int hh = col >> 6, dd = col & 63;
                int dh = dd >> 5, q5v = dd & 31;
                float bb = bias[col];
                int row0 = m0 + wm + mt * 16 + g * 4;
                int bbi = row0 >> 10, nn = row0 & 1023;
                int wa = nn >> 7, kt = (nn >> 5) & 3;
                int ks = (nn >> 4) & 1, hi2 = (nn >> 3) & 1, j0 = nn & 7;
                f16x4 pk;
#pragma unroll
                for (int i = 0; i < 4; ++i) pk[i] = (_Float16)(acc[mt][nt][i] + bb);
                size_t off = ((((((size_t)(bbi * 16 + hh) * 8 + wa) * 4 + kt) * 2 + dh) * 2 + ks) * 32 +
                              q5v) * 16 + hi2 * 8 + j0;
                *(f16x4*)&vT[off] = pk;
            }
    }
}

// ---------------------------------------------------------------------------
// fused attention v8: 512 threads (8 waves), NO K/Q/V LDS staging.
// All fragment loads are fully-coalesced 1KB global_load_dwordx4 from the
// tiled qT/kT/vT layouts (v7 was LDS-stage-serialized + 4-way bank conflicts).
// Math unchanged: swapped QK^T (S^T, q=lane&31), pack+half-wave exchange,
// PV + MFMA-avg (bsel), Obuf f32 cross-wave k-reduce, non-atomic partials.
// LDS = Obuf 68KB + red 2KB only.
// ---------------------------------------------------------------------------
__global__ __launch_bounds__(512, 2) void attn(
    const _Float16* __restrict__ qT, const _Float16* __restrict__ kT,
    const _Float16* __restrict__ vT, float* __restrict__ O,
    _Float16* __restrict__ part0, _Float16* __restrict__ part1) {
    extern __shared__ __align__(16) char smem[];
    float* Obuf = (float*)smem;                 // [8][32][68] f32 = 69632
    float* red_m = (float*)(smem + 69632);      // [8][32]
    float* red_l = red_m + 256;                 // [8][32]

    const int tid = threadIdx.x, w = tid >> 6, lane = tid & 63;
    const int q5 = lane & 31, hi = lane >> 5;

    // XCD-aware: group = f & 7 -> all 32 q-tiles of a (chunk,b2) group per XCD
    const int f = blockIdx.x;
    const int grp = f & 7, qt = f >> 3, q0 = qt * 32;
    const int chunk = grp & 1, b2 = grp >> 1;

    const int lofs = q5 * 16 + hi * 8;  // per-lane offset within a 1KB frag page

    // Bsel B-fragments: Bsel[ks](k,n) = (k == n&15 && n>>4 == ks)
    f16x8 bsel[2];
#pragma unroll
    for (int ks = 0; ks < 2; ++ks)
#pragma unroll
        for (int j = 0; j < 8; ++j)
            bsel[ks][j] = (hi * 8 + j == (q5 & 15) && (q5 >> 4) == ks)
                              ? (_Float16)1.0f : (_Float16)0.0f;

    f32x16 aacc[4] = {};

#pragma unroll 1
    for (int p = 0; p < 8; ++p) {
        const int m = b2 * 16 + chunk * 8 + p;
        const int b = m & 3, h = m >> 2;
        const int head = b * 16 + h;
        const _Float16* qb = qT + ((size_t)head * 32 + qt) * 2048 + lofs;
        const _Float16* kb = kT + ((size_t)head * 8 + w) * 8192 + lofs;
        const _Float16* vb = vT + ((size_t)head * 8 + w) * 8192 + lofs;

        // ---- Q fragments (4 coalesced loads) ----
        f16x8 qf[4];
#pragma unroll
        for (int dc = 0; dc < 4; ++dc) qf[dc] = *(const f16x8*)(qb + dc * 512);

        // ---- pipelined: reduce + store O of pair p-1 (overlaps loads) ----
        if (p) {
            int mp = m - 1; int bp = mp & 3, hp = mp >> 2;
            int qq = tid >> 4, dd = (tid & 15) * 4;
            f32x4 acc = {};
#pragma unroll
            for (int buf = 0; buf < 8; ++buf) {
                f32x4 v = *(f32x4*)&Obuf[buf * 2176 + qq * 68 + dd];
                acc += v;
            }
            *(f32x4*)(O + (size_t)bp * 1048576 + (size_t)(q0 + qq) * 1024 + hp * 64 + dd) = acc;
        }

        // ---- QK^T: per kt, 4 coalesced K loads + 4 MFMA ----
        f32x16 s[4] = {};
#pragma unroll
        for (int kt = 0; kt < 4; ++kt) {
            f16x8 kf[4];
#pragma unroll
            for (int dc = 0; dc < 4; ++dc)
                kf[dc] = *(const f16x8*)(kb + kt * 2048 + dc * 512);
#pragma unroll
            for (int dc = 0; dc < 4; ++dc) s[kt] = MFMA32(kf[dc], qf[dc], s[kt]);
        }

        // ---- local (wave) max + exp + sum ----
        float pm = -3.0e38f;
#pragma unroll
        for (int kt = 0; kt < 4; ++kt)
#pragma unroll
            for (int r = 0; r < 16; ++r) pm = fmaxf(pm, s[kt][r]);
        pm = fmaxf(pm, __shfl_xor(pm, 32, 64));
        float l = 0.f;
#pragma unroll
        for (int kt = 0; kt < 4; ++kt)
#pragma unroll
            for (int r = 0; r < 16; ++r) {
                float e = exp2f((s[kt][r] - pm) * C1);
                s[kt][r] = e; l += e;
            }
        l += __shfl_xor(l, 32, 64);
        if (hi == 0) { red_m[w * 32 + q5] = pm; red_l[w * 32 + q5] = l; }
        __syncthreads();  // A

        // ---- global fixup over 8 waves (hi-split 4+4, shfl combine) ----
        float mr[4], lr[4], M = -3.0e38f;
#pragma unroll
        for (int t = 0; t < 4; ++t) {
            int wv = hi * 4 + t;
            mr[t] = red_m[wv * 32 + q5];
            lr[t] = red_l[wv * 32 + q5];
            M = fmaxf(M, mr[t]);
        }
        M = fmaxf(M, __shfl_xor(M, 32, 64));
        float L = 0.f;
#pragma unroll
        for (int t = 0; t < 4; ++t) L += lr[t] * exp2f((mr[t] - M) * C1);
        L += __shfl_xor(L, 32, 64);
        const float sc = exp2f((pm - M) * C1) / L;

        // ---- pack P = e*sc -> f16 pairs, half-wave exchange -> av ----
        u32x4 av[4][2];
#pragma unroll
        for (int kt = 0; kt < 4; ++kt) {
            unsigned pw[8];
#pragma unroll
            for (int r2 = 0; r2 < 8; ++r2) {
                f16x2 t2;
                t2[0] = (_Float16)(s[kt][2 * r2] * sc);
                t2[1] = (_Float16)(s[kt][2 * r2 + 1] * sc);
                pw[r2] = __builtin_bit_cast(unsigned, t2);
            }
            unsigned recv[2][2];
#pragma unroll
            for (int ks = 0; ks < 2; ++ks)
#pragma unroll
                for (int d = 0; d < 2; ++d) {
                    unsigned send = hi ? pw[4 * ks + d] : pw[4 * ks + 2 + d];
                    recv[ks][d] = (unsigned)__shfl_xor((int)send, 32, 64);
                }
#pragma unroll
            for (int ks = 0; ks < 2; ++ks) {
                unsigned own0 = hi ? pw[4 * ks + 2] : pw[4 * ks + 0];
                unsigned own1 = hi ? pw[4 * ks + 3] : pw[4 * ks + 1];
                u32x4 a;
                a[0] = hi ? recv[ks][0] : own0;
                a[1] = hi ? recv[ks][1] : own1;
                a[2] = hi ? own0 : recv[ks][0];
                a[3] = hi ? own1 : recv[ks][1];
                av[kt][ks] = a;
            }
        }

        // ---- PV + MFMA-avg: per kt, 4 coalesced V loads + 6 MFMA ----
        f32x16 o0 = {}, o1 = {};
#pragma unroll
        for (int kt = 0; kt < 4; ++kt) {
            f16x8 vf[2][2];
#pragma unroll
            for (int dh = 0; dh < 2; ++dh)
#pragma unroll
                for (int ks = 0; ks < 2; ++ks)
                    vf[dh][ks] = *(const f16x8*)(vb + kt * 2048 + dh * 1024 + ks * 512);
#pragma unroll
            for (int ks = 0; ks < 2; ++ks) {
                f16x8 pa = __builtin_bit_cast(f16x8, av[kt][ks]);
                o0 = MFMA32(pa, vf[0][ks], o0);
                o1 = MFMA32(pa, vf[1][ks], o1);
            }
            aacc[kt] = MFMA32(__builtin_bit_cast(f16x8, av[kt][0]), bsel[0], aacc[kt]);
            aacc[kt] = MFMA32(__builtin_bit_cast(f16x8, av[kt][1]), bsel[1], aacc[kt]);
        }

        // ---- O partials to Obuf ----
        float* ob = Obuf + w * 2176;
#pragma unroll
        for (int r = 0; r < 16; ++r) {
            int qq = (r & 3) + 8 * (r >> 2) + 4 * hi;
            ob[qq * 68 + q5] = o0[r];
            ob[qq * 68 + 32 + q5] = o1[r];
        }
        __syncthreads();  // C
    }

    // ---- final reduce + store O for pair 7 ----
    {
        int mp = b2 * 16 + chunk * 8 + 7; int bp = mp & 3, hp = mp >> 2;
        int qq = tid >> 4, dd = (tid & 15) * 4;
        f32x4 acc = {};
#pragma unroll
        for (int buf = 0; buf < 8; ++buf) {
            f32x4 v = *(f32x4*)&Obuf[buf * 2176 + qq * 68 + dd];
            acc += v;
        }
        *(f32x4*)(O + (size_t)bp * 1048576 + (size_t)(q0 + qq) * 1024 + hp * 64 + dd) = acc;
    }

    // ---- A_avg tail: non-atomic f16 partial stores (one writer/element) ----
    {
        _Float16* pb = (chunk ? part1 : part0) + ((size_t)b2 * 1024 + q0) * 1024;
#pragma unroll
        for (int kt = 0; kt < 4; ++kt) {
            int k = w * 128 + kt * 32 + q5;
#pragma unroll
            for (int r = 0; r < 16; ++r) {
                int qq = (r & 3) + 8 * (r >> 2) + 4 * hi;
                pb[(size_t)qq * 1024 + k] = (_Float16)aacc[kt][r];
            }
        }
    }
}

// ---------------------------------------------------------------------------
// A_avg = (part0 + part1) / 16
// ---------------------------------------------------------------------------
__global__ void add_avg(const _Float16* __restrict__ p0,
                        const _Float16* __restrict__ p1,
                        float* __restrict__ out) {
    int i = blockIdx.x * blockDim.x + threadIdx.x;  // groups of 8
    f16x8 a = ((const f16x8*)p0)[i];
    f16x8 b = ((const f16x8*)p1)[i];
    f32x4 r0, r1;
#pragma unroll
    for (int j = 0; j < 4; ++j) r0[j] = ((float)a[j] + (float)b[j]) * 0.0625f;
#pragma unroll
    for (int j = 0; j < 4; ++j) r1[j] = ((float)a[4 + j] + (float)b[4 + j]) * 0.0625f;
    *(f32x4*)&out[8 * i] = r0;
    *(f32x4*)&out[8 * i + 4] = r1;
}

// ---------------------------------------------------------------------------
extern "C" void kernel_launch(void* const* d_in, const int* in_sizes, int n_in,
                              void* d_out, int out_size, void* d_ws, size_t ws_size,
                              hipStream_t stream) {
    if (ws_size < ((size_t)46 << 20)) return;  // need 46 MB scratch

    const float* Q  = (const float*)d_in[0];
    const float* K  = (const float*)d_in[1];
    const float* Wq = (const float*)d_in[2];
    const float* bq = (const float*)d_in[3];
    const float* Wk = (const float*)d_in[4];
    const float* bk = (const float*)d_in[5];
    const float* Wv = (const float*)d_in[6];
    const float* bv = (const float*)d_in[7];

    char* ws = (char*)d_ws;
    _Float16* Qh  = (_Float16*)(ws);                      //  8 MB
    _Float16* Kh  = (_Float16*)(ws + ((size_t)8 << 20));  //  8 MB
    _Float16* Wqh = (_Float16*)(ws + ((size_t)16 << 20)); //  2 MB
    _Float16* Wkh = (_Float16*)(ws + ((size_t)18 << 20)); //  2 MB
    _Float16* Wvh = (_Float16*)(ws + ((size_t)20 << 20)); //  2 MB
    _Float16* qT  = (_Float16*)(ws + ((size_t)22 << 20)); //  8 MB (tiled)
    _Float16* kT  = (_Float16*)(ws + ((size_t)30 << 20)); //  8 MB (tiled)
    _Float16* vT  = (_Float16*)(ws + ((size_t)38 << 20)); //  8 MB (tiled)
    // partials alias Qh/Kh (dead after proj_gemm)
    _Float16* part0 = (_Float16*)(ws);                     // 8 MB
    _Float16* part1 = (_Float16*)(ws + ((size_t)8 << 20)); // 8 MB

    float* O = (float*)d_out;
    float* Aavg = O + (size_t)4 * 1024 * 1024;

    // 1) convert inputs to fp16
    cvt_all<<<dim3(1441792 / 256), 256, 0, stream>>>(Q, K, Wq, Wk, Wv, Qh);

    // 2) three projection GEMMs (tiled outputs)
    proj_gemm<<<dim3(32, 8, 3), 256, 0, stream>>>(Qh, Kh, Wqh, Wkh, Wvh,
                                                  bq, bk, bv, qT, kT, vT);

    // 3) fused attention: 256 blocks x 512 threads, 71680 B LDS
    const int SMEM = 71680;
    hipFuncSetAttribute((const void*)attn, hipFuncAttributeMaxDynamicSharedMemorySize, SMEM);
    attn<<<dim3(256), 512, SMEM, stream>>>(qT, kT, vT, O, part0, part1);

    // 4) A_avg = (part0 + part1) / 16
    add_avg<<<dim3(2048), 256, 0, stream>>>(part0, part1, Aavg);
}